// Round 4
// baseline (7768.901 us; speedup 1.0000x reference)
//
#include <hip/hip_runtime.h>
#include <math.h>

typedef _Float16 f16;
typedef _Float16 f16x8 __attribute__((ext_vector_type(8)));
typedef float f32x4 __attribute__((ext_vector_type(4)));

namespace {

constexpr int NT = 512;     // 8 waves
constexpr int M  = 64;      // agents per block
constexpr int HORIZON = 64;

__device__ __forceinline__ void mfma3(f32x4& acc, f16x8 ah, f16x8 al, f16x8 bh, f16x8 bl)
{
    acc = __builtin_amdgcn_mfma_f32_16x16x32_f16(ah, bh, acc, 0, 0, 0);
    acc = __builtin_amdgcn_mfma_f32_16x16x32_f16(al, bh, acc, 0, 0, 0);
    acc = __builtin_amdgcn_mfma_f32_16x16x32_f16(ah, bl, acc, 0, 0, 0);
}

// LDS-staged-B MFMA rollout. Every global weight load is a wave-contiguous
// 256 B row segment (R1's proven ~100% L2-hit shape); B-frags come from LDS.
__global__ __launch_bounds__(NT, 2)
void rollout_kernel(const float* __restrict__ pos0, const float* __restrict__ wind,
                    const float* __restrict__ w1, const float* __restrict__ b1,
                    const float* __restrict__ w2, const float* __restrict__ b2,
                    const float* __restrict__ w3, const float* __restrict__ b3,
                    const float* __restrict__ wmu, const float* __restrict__ bmu,
                    float* __restrict__ out)
{
    // activations, f16 hi/lo, XOR-chunk swizzle: (row,k) -> row*256 + ((k>>3 ^ (row&31))<<3) + (k&7)
    __shared__ __align__(16) f16 hA_hi[M*256];       // 32 KB
    __shared__ __align__(16) f16 hA_lo[M*256];       // 32 KB
    // staged weight K-chunk (32 rows x 256 cols), frag order [q][col][j]
    __shared__ __align__(16) f16 S_hi[2][8192];      // 32 KB
    __shared__ __align__(16) f16 S_lo[2][8192];      // 32 KB
    __shared__ __align__(16) float paL[4][2][M];     // 2 KB

    const int t  = threadIdx.x;
    const int l  = t & 63;
    const int wv = t >> 6;         // 8 waves
    const int lr = l & 15;
    const int q  = l >> 4;
    const int rh = wv & 1;         // row half: rows [32rh, 32rh+32)
    const int cq = wv >> 1;        // col quarter: cols [64cq, 64cq+64)

    float b1r[4], b2r[4], b3r[4], wmur[4][2];
    #pragma unroll
    for (int nt = 0; nt < 4; ++nt) {
        int col = 64*cq + 16*nt + lr;
        b1r[nt] = b1[col]; b2r[nt] = b2[col]; b3r[nt] = b3[col];
        wmur[nt][0] = wmu[2*col]; wmur[nt][1] = wmu[2*col + 1];
    }
    const float bm0 = bmu[0], bm1 = bmu[1];

    // w1 B-frags hoisted to registers (tiny, step-invariant)
    f16x8 w1h[4], w1l[4];
    #pragma unroll
    for (int nt = 0; nt < 4; ++nt) {
        int n = 64*cq + 16*nt + lr;
        #pragma unroll
        for (int j = 0; j < 8; ++j) {
            int k = q*8 + j;
            float v = (k < 13) ? w1[k*256 + n] : 0.f;
            f16 h = (f16)v;
            w1h[nt][j] = h;
            w1l[nt][j] = (f16)(v - (float)h);
        }
    }

    float px=0.f, py=0.f, wx=0.f, wy=0.f;
    float mx_s=-1e30f, sum_s=0.f, mx_r=-1e30f, sum_r=0.f;
    if (t < M) {
        int g = blockIdx.x*M + t;
        px = pos0[2*g]; py = pos0[2*g+1]; wx = wind[2*g]; wy = wind[2*g+1];
    }

    float Freg[2][2][8];   // [buf][slot-group][j] prefetched fp32 weights

    // fetch one 32-row chunk: wave-contiguous 256 B per instruction (R1 shape)
    auto fetchChunk = [&](const float* __restrict__ W, int kc, float (&F)[2][8]) {
        #pragma unroll
        for (int g = 0; g < 2; ++g) {
            int sg = wv*2 + g;
            int qw = sg >> 2, colb = (sg & 3) << 6;
            const float* p = W + (kc*32 + 8*qw)*256 + colb + l;
            #pragma unroll
            for (int j = 0; j < 8; ++j) F[g][j] = p[j*256];
        }
    };
    // convert + write chunk into stage buffer (contiguous b128 writes)
    auto writeChunk = [&](int buf, float (&F)[2][8]) {
        #pragma unroll
        for (int g = 0; g < 2; ++g) {
            int sg = wv*2 + g;
            int qw = sg >> 2, colb = (sg & 3) << 6;
            f16x8 hi, lo;
            #pragma unroll
            for (int j = 0; j < 8; ++j) {
                float v = F[g][j];
                f16 h = (f16)v;
                hi[j] = h;
                lo[j] = (f16)(v - (float)h);
            }
            int off = (qw*256 + colb + l)*8;
            *(f16x8*)(S_hi[buf] + off) = hi;
            *(f16x8*)(S_lo[buf] + off) = lo;
        }
    };

    // C-layout writeback with relu + hi/lo split into swizzled hA
    auto writeback = [&](f32x4 (&a)[2][4]) {
        #pragma unroll
        for (int mt = 0; mt < 2; ++mt)
          #pragma unroll
          for (int nt = 0; nt < 4; ++nt)
            #pragma unroll
            for (int r = 0; r < 4; ++r) {
                float h = fmaxf(a[mt][nt][r], 0.f);
                f16 hi = (f16)h;
                f16 lo = (f16)(h - (float)hi);
                int row = 32*rh + 16*mt + 4*q + r;
                int col = 64*cq + 16*nt + lr;
                int off = row*256 + (((col >> 3) ^ (row & 31)) << 3) + (col & 7);
                hA_hi[off] = hi;
                hA_lo[off] = lo;
            }
    };

    // staged 256-K GEMM; prefetches Wcur chunks kc+2, then Wnext chunks 0/1
    auto gemmS = [&](const float* __restrict__ Wcur, const float* __restrict__ Wnext,
                     f32x4 (&a)[2][4]) {
        #pragma unroll
        for (int kc = 0; kc < 8; ++kc) {
            const int p = kc & 1;
            f16x8 ah[2], al[2], bh[4], bl[4];
            #pragma unroll
            for (int mt = 0; mt < 2; ++mt) {
                int row = 32*rh + 16*mt + lr;
                int off = row*256 + (((kc*4 + q) ^ (row & 31)) << 3);
                ah[mt] = *(const f16x8*)(hA_hi + off);
                al[mt] = *(const f16x8*)(hA_lo + off);
            }
            #pragma unroll
            for (int nt = 0; nt < 4; ++nt) {
                int off = (q*256 + 64*cq + 16*nt + lr)*8;
                bh[nt] = *(const f16x8*)(S_hi[p] + off);
                bl[nt] = *(const f16x8*)(S_lo[p] + off);
            }
            if (kc < 6)       fetchChunk(Wcur,  kc + 2, Freg[kc & 1]);
            else if (Wnext)   fetchChunk(Wnext, kc - 6, Freg[kc & 1]);
            if (kc < 7)       writeChunk(1 - p, Freg[(kc + 1) & 1]);
            #pragma unroll
            for (int mt = 0; mt < 2; ++mt)
              #pragma unroll
              for (int nt = 0; nt < 4; ++nt)
                mfma3(a[mt][nt], ah[mt], al[mt], bh[nt], bl[nt]);
            __syncthreads();
        }
    };

    for (int step = 0; step < HORIZON; ++step) {
        // ---- P0: obs (agents = wave 0), overlaid at hA base, stride 40 ----
        if (t < M) {
            float o[16];
            float dx0 = px - 1.75f, dy0 = py - 1.75f;
            float dx1 = px - 1.75f, dy1 = py - 3.75f;
            float dx2 = px - 3.75f, dy2 = py - 2.00f;
            o[0] = px*0.1f;        o[1] = py*0.1f;
            o[2] = (4.f-px)*0.1f;  o[3] = (3.f-py)*0.1f;
            o[4] = -dx0*0.1f;      o[5] = -dy0*0.1f;
            o[6] = -dx1*0.1f;      o[7] = -dy1*0.1f;
            o[8] = -dx2*0.1f;      o[9] = -dy2*0.1f;
            o[10] = sqrtf(dx0*dx0+dy0*dy0+1e-9f) - 0.38f;
            o[11] = sqrtf(dx1*dx1+dy1*dy1+1e-9f) - 0.42f;
            o[12] = sqrtf(dx2*dx2+dy2*dy2+1e-9f) - 0.34f;
            o[13] = 0.f; o[14] = 0.f; o[15] = 0.f;
            #pragma unroll
            for (int k = 0; k < 32; ++k) {
                float v = (k < 16) ? o[k] : 0.f;
                f16 hi = (f16)v;
                hA_hi[t*40 + k] = hi;
                hA_lo[t*40 + k] = (f16)(v - (float)hi);
            }
        }
        __syncthreads();   // B1: obsA visible; prev-step paL reads done

        f32x4 acc[2][4];

        // ---- L1 (obs->256) + prefetch w2 chunk0 ----
        fetchChunk(w2, 0, Freg[0]);
        #pragma unroll
        for (int mt = 0; mt < 2; ++mt)
          #pragma unroll
          for (int nt = 0; nt < 4; ++nt)
            acc[mt][nt] = (f32x4){b1r[nt], b1r[nt], b1r[nt], b1r[nt]};
        {
            f16x8 ah[2], al[2];
            #pragma unroll
            for (int mt = 0; mt < 2; ++mt) {
                int off = (32*rh + 16*mt + lr)*40 + q*8;
                ah[mt] = *(const f16x8*)(hA_hi + off);
                al[mt] = *(const f16x8*)(hA_lo + off);
            }
            #pragma unroll
            for (int mt = 0; mt < 2; ++mt)
              #pragma unroll
              for (int nt = 0; nt < 4; ++nt)
                mfma3(acc[mt][nt], ah[mt], al[mt], w1h[nt], w1l[nt]);
        }
        __syncthreads();   // B2: obs reads done; stage bufs free
        writeback(acc);    // h1 -> hA
        writeChunk(0, Freg[0]);
        fetchChunk(w2, 1, Freg[1]);
        __syncthreads();   // B3: h1 + S0 visible

        // ---- L2 ----
        #pragma unroll
        for (int mt = 0; mt < 2; ++mt)
          #pragma unroll
          for (int nt = 0; nt < 4; ++nt)
            acc[mt][nt] = (f32x4){b2r[nt], b2r[nt], b2r[nt], b2r[nt]};
        gemmS(w2, w3, acc);           // tail prefetches w3 chunks 0,1
        writeback(acc);               // h2 -> hA (gemm ended with barrier)
        writeChunk(0, Freg[0]);       // w3 chunk0 -> S0
        __syncthreads();              // B12: h2 + S0 visible

        // ---- L3 + fused L4 ----
        #pragma unroll
        for (int mt = 0; mt < 2; ++mt)
          #pragma unroll
          for (int nt = 0; nt < 4; ++nt)
            acc[mt][nt] = (f32x4){b3r[nt], b3r[nt], b3r[nt], b3r[nt]};
        gemmS(w3, nullptr, acc);
        {
            float pa[2][4][2];
            #pragma unroll
            for (int mt = 0; mt < 2; ++mt)
              #pragma unroll
              for (int r = 0; r < 4; ++r)
                { pa[mt][r][0] = 0.f; pa[mt][r][1] = 0.f; }
            #pragma unroll
            for (int mt = 0; mt < 2; ++mt)
              #pragma unroll
              for (int nt = 0; nt < 4; ++nt)
                #pragma unroll
                for (int r = 0; r < 4; ++r) {
                    float h = fmaxf(acc[mt][nt][r], 0.f);
                    pa[mt][r][0] = fmaf(h, wmur[nt][0], pa[mt][r][0]);
                    pa[mt][r][1] = fmaf(h, wmur[nt][1], pa[mt][r][1]);
                }
            #pragma unroll
            for (int s = 0; s < 4; ++s)
                #pragma unroll
                for (int mt = 0; mt < 2; ++mt)
                  #pragma unroll
                  for (int r = 0; r < 4; ++r) {
                      pa[mt][r][0] += __shfl_xor(pa[mt][r][0], 1 << s, 64);
                      pa[mt][r][1] += __shfl_xor(pa[mt][r][1], 1 << s, 64);
                  }
            if (lr == 0) {
                #pragma unroll
                for (int mt = 0; mt < 2; ++mt)
                  #pragma unroll
                  for (int c = 0; c < 2; ++c) {
                      f32x4 v = {pa[mt][0][c], pa[mt][1][c], pa[mt][2][c], pa[mt][3][c]};
                      *(f32x4*)&paL[cq][c][32*rh + 16*mt + 4*q] = v;
                  }
            }
        }
        __syncthreads();   // B21: paL visible; all hA reads done

        // ---- P5: action, dynamics, STREL (wave 0) ----
        if (t < M) {
            float s0 = bm0 + paL[0][0][t] + paL[1][0][t] + paL[2][0][t] + paL[3][0][t];
            float s1 = bm1 + paL[0][1][t] + paL[1][1][t] + paL[2][1][t] + paL[3][1][t];
            float ax = fminf(fmaxf(s0, -1.f), 1.f);
            float ay = fminf(fmaxf(s1, -1.f), 1.f);
            float vx = 2.f*ax + wx, vy = 2.f*ay + wy;
            #pragma unroll
            for (int s = 0; s < 4; ++s) {
                px = fminf(fmaxf(px + 0.0625f*vx, -4.f), 10.f);
                py = fminf(fmaxf(py + 0.0625f*vy, -4.f), 10.f);
            }
            float dx0 = px - 1.75f, dy0 = py - 1.75f;
            float dx1 = px - 1.75f, dy1 = py - 3.75f;
            float dx2 = px - 3.75f, dy2 = py - 2.00f;
            float c0 = sqrtf(dx0*dx0+dy0*dy0+1e-9f) - 0.38f;
            float c1 = sqrtf(dx1*dx1+dy1*dy1+1e-9f) - 0.42f;
            float c2 = sqrtf(dx2*dx2+dy2*dy2+1e-9f) - 0.34f;
            float cmin = fminf(c0, fminf(c1, c2));
            float ssum = expf(-50.f*(c0-cmin)) + expf(-50.f*(c1-cmin)) + expf(-50.f*(c2-cmin));
            float safe = cmin - logf(ssum)/50.f;
            float gdx = px - 4.f, gdy = py - 3.f;
            float reach = 0.45f - sqrtf(gdx*gdx+gdy*gdy+1e-9f);
            float xs = -8.f*safe;
            if (xs > mx_s) { sum_s = sum_s*expf(mx_s - xs) + 1.f; mx_s = xs; }
            else           { sum_s += expf(xs - mx_s); }
            float xr = 8.f*reach;
            if (xr > mx_r) { sum_r = sum_r*expf(mx_r - xr) + 1.f; mx_r = xr; }
            else           { sum_r += expf(xr - mx_r); }
        }
    }

    if (t < M) {
        float rs = -(mx_s + logf(sum_s)) * 0.125f;
        float rr =  (mx_r + logf(sum_r)) * 0.125f;
        float u0 = -8.f*rs, u1 = -8.f*rr;
        float mu = fmaxf(u0, u1);
        float rho = -(mu + logf(expf(u0-mu) + expf(u1-mu))) * 0.125f;
        out[blockIdx.x*M + t] = rho;
    }
}

} // namespace

extern "C" void kernel_launch(void* const* d_in, const int* in_sizes, int n_in,
                              void* d_out, int out_size, void* d_ws, size_t ws_size,
                              hipStream_t stream)
{
    const float* pos0 = (const float*)d_in[0];
    const float* wind = (const float*)d_in[1];
    const float* w1   = (const float*)d_in[2];
    const float* b1   = (const float*)d_in[3];
    const float* w2   = (const float*)d_in[4];
    const float* b2   = (const float*)d_in[5];
    const float* w3   = (const float*)d_in[6];
    const float* b3   = (const float*)d_in[7];
    const float* wmu  = (const float*)d_in[8];
    const float* bmu  = (const float*)d_in[9];
    float* out = (float*)d_out;
    (void)d_ws; (void)ws_size;

    const int B = in_sizes[0] / 2;     // 32768 agents
    const int blocks = B / M;          // 512 blocks, 1/CU (LDS 130 KB), 2 rounds
    rollout_kernel<<<blocks, NT, 0, stream>>>(pos0, wind, w1, b1, w2, b2,
                                              w3, b3, wmu, bmu, out);
}

// Round 5
// 6983.103 us; speedup vs baseline: 1.1125x; 1.1125x over previous
//
#include <hip/hip_runtime.h>
#include <math.h>

typedef _Float16 f16;
typedef _Float16 f16x8 __attribute__((ext_vector_type(8)));
typedef float f32x4 __attribute__((ext_vector_type(4)));

namespace {

constexpr int NT = 512;     // 8 waves, 1 block/CU
constexpr int M  = 128;     // agents per block
constexpr int HORIZON = 64;

__device__ __forceinline__ void mfma3(f32x4& acc, f16x8 ah, f16x8 al, f16x8 bh, f16x8 bl)
{
    acc = __builtin_amdgcn_mfma_f32_16x16x32_f16(ah, bh, acc, 0, 0, 0);
    acc = __builtin_amdgcn_mfma_f32_16x16x32_f16(al, bh, acc, 0, 0, 0);
    acc = __builtin_amdgcn_mfma_f32_16x16x32_f16(ah, bl, acc, 0, 0, 0);
}

// fetch one 32x256 fp32 chunk: every global instr is a wave-contiguous 256 B row seg
#define FETCH_CHUNK(Wp, kc, Fv) do {                                         \
    const float* _p0 = (Wp) + ((kc)*32 + q0*8)*256 + colf;                   \
    const float* _p1 = (Wp) + ((kc)*32 + (q0+2)*8)*256 + colf;               \
    _Pragma("unroll")                                                        \
    for (int _j = 0; _j < 8; ++_j) {                                         \
        (Fv)[_j]     = _p0[_j*256];                                          \
        (Fv)[8 + _j] = _p1[_j*256];                                          \
    }                                                                        \
} while (0)

// convert fp32 -> f16 hi/lo and store to stage (contiguous b128 writes)
#define WRITE_CHUNK(Fv) do {                                                 \
    f16x8 _h0, _l0, _h1, _l1;                                                \
    _Pragma("unroll")                                                        \
    for (int _j = 0; _j < 8; ++_j) {                                         \
        float _v = (Fv)[_j];      f16 _h = (f16)_v;                          \
        _h0[_j] = _h; _l0[_j] = (f16)(_v - (float)_h);                       \
        _v = (Fv)[8 + _j];        _h = (f16)_v;                              \
        _h1[_j] = _h; _l1[_j] = (f16)(_v - (float)_h);                       \
    }                                                                        \
    *(f16x8*)(S_hi + (q0*256 + colf)*8)     = _h0;                           \
    *(f16x8*)(S_lo + (q0*256 + colf)*8)     = _l0;                           \
    *(f16x8*)(S_hi + ((q0+2)*256 + colf)*8) = _h1;                           \
    *(f16x8*)(S_lo + ((q0+2)*256 + colf)*8) = _l1;                           \
} while (0)

// relu + hi/lo split of acc tile into swizzled hA
#define WRITEBACK_ACC() do {                                                 \
    _Pragma("unroll")                                                        \
    for (int _mt = 0; _mt < 4; ++_mt) {                                      \
      _Pragma("unroll")                                                      \
      for (int _nt = 0; _nt < 4; ++_nt) {                                    \
        _Pragma("unroll")                                                    \
        for (int _r = 0; _r < 4; ++_r) {                                     \
            float _h = fmaxf(acc[_mt][_nt][_r], 0.f);                        \
            f16 _hi = (f16)_h;                                               \
            f16 _lo = (f16)(_h - (float)_hi);                                \
            int _row = 64*rh + 16*_mt + 4*q + _r;                            \
            int _col = 64*cq + 16*_nt + lr;                                  \
            int _off = _row*256 + (((_col >> 3) ^ (_row & 31)) << 3) + (_col & 7); \
            hA_hi[_off] = _hi;                                               \
            hA_lo[_off] = _lo;                                               \
        }                                                                    \
      }                                                                      \
    }                                                                        \
} while (0)

// observation write for agent thread t (< M): 32 f16 hi/lo, stride-40 rows
#define OBS_WRITE() do {                                                     \
    float _o[32];                                                            \
    float _dx0 = px - 1.75f, _dy0 = py - 1.75f;                              \
    float _dx1 = px - 1.75f, _dy1 = py - 3.75f;                              \
    float _dx2 = px - 3.75f, _dy2 = py - 2.00f;                              \
    _o[0] = px*0.1f;        _o[1] = py*0.1f;                                 \
    _o[2] = (4.f-px)*0.1f;  _o[3] = (3.f-py)*0.1f;                           \
    _o[4] = -_dx0*0.1f;     _o[5] = -_dy0*0.1f;                              \
    _o[6] = -_dx1*0.1f;     _o[7] = -_dy1*0.1f;                              \
    _o[8] = -_dx2*0.1f;     _o[9] = -_dy2*0.1f;                              \
    _o[10] = sqrtf(_dx0*_dx0+_dy0*_dy0+1e-9f) - 0.38f;                       \
    _o[11] = sqrtf(_dx1*_dx1+_dy1*_dy1+1e-9f) - 0.42f;                       \
    _o[12] = sqrtf(_dx2*_dx2+_dy2*_dy2+1e-9f) - 0.34f;                       \
    _Pragma("unroll")                                                        \
    for (int _k = 13; _k < 32; ++_k) _o[_k] = 0.f;                           \
    _Pragma("unroll")                                                        \
    for (int _c = 0; _c < 4; ++_c) {                                         \
        f16x8 _hi, _lo;                                                      \
        _Pragma("unroll")                                                    \
        for (int _j = 0; _j < 8; ++_j) {                                     \
            float _v = _o[_c*8 + _j];                                        \
            f16 _h = (f16)_v;                                                \
            _hi[_j] = _h; _lo[_j] = (f16)(_v - (float)_h);                   \
        }                                                                    \
        *(f16x8*)(hA_hi + t*40 + _c*8) = _hi;                                \
        *(f16x8*)(hA_lo + t*40 + _c*8) = _lo;                                \
    }                                                                        \
} while (0)

__global__ __launch_bounds__(NT, 2)
void rollout_kernel(const float* __restrict__ pos0, const float* __restrict__ wind,
                    const float* __restrict__ w1, const float* __restrict__ b1,
                    const float* __restrict__ w2, const float* __restrict__ b2,
                    const float* __restrict__ w3, const float* __restrict__ b3,
                    const float* __restrict__ wmu, const float* __restrict__ bmu,
                    float* __restrict__ out)
{
    // activations (f16 hi/lo), XOR-chunk swizzle: (row,k) -> row*256 + ((k>>3 ^ (row&31))<<3) + (k&7)
    __shared__ __align__(16) f16 hA_hi[M*256];   // 65536 B
    __shared__ __align__(16) f16 hA_lo[M*256];   // 65536 B
    // single-buffered weight stage: chunk layout [q][col][j], q = k-octet
    __shared__ __align__(16) f16 S_hi[8192];     // 16384 B
    __shared__ __align__(16) f16 S_lo[8192];     // 16384 B  -> total 163840 B
    // L4 partials overlay: dead h2 rows 64..71 of hA_hi (written after last hA read)
    float* paL = (float*)(hA_hi + 16384);        // [4 cq][2 c][128 row] = 4096 B

    const int t  = threadIdx.x;
    const int l  = t & 63;
    const int wv = t >> 6;         // 8 waves
    const int lr = l & 15;
    const int q  = l >> 4;
    const int rh = wv & 1;         // rows [64*rh, 64*rh+64)
    const int cq = wv >> 1;        // cols [64*cq, 64*cq+64)
    const int colf = t & 255;      // fetch column
    const int q0   = t >> 8;       // fetch row-octet base (0/1; +2 for 2nd slot)

    float b1r[4], b2r[4], b3r[4], wmur[4][2];
    #pragma unroll
    for (int nt = 0; nt < 4; ++nt) {
        int col = 64*cq + 16*nt + lr;
        b1r[nt] = b1[col]; b2r[nt] = b2[col]; b3r[nt] = b3[col];
        wmur[nt][0] = wmu[2*col]; wmur[nt][1] = wmu[2*col + 1];
    }
    const float bm0 = bmu[0], bm1 = bmu[1];

    // w1 B-frags hoisted (step-invariant): lane l holds W1[k=q*8+j][col]
    f16x8 w1h[4], w1l[4];
    #pragma unroll
    for (int nt = 0; nt < 4; ++nt) {
        int n = 64*cq + 16*nt + lr;
        #pragma unroll
        for (int j = 0; j < 8; ++j) {
            int k = q*8 + j;
            float v = (k < 13) ? w1[k*256 + n] : 0.f;
            f16 h = (f16)v;
            w1h[nt][j] = h;
            w1l[nt][j] = (f16)(v - (float)h);
        }
    }

    float px=0.f, py=0.f, wx=0.f, wy=0.f;
    float mx_s=-1e30f, sum_s=0.f, mx_r=-1e30f, sum_r=0.f;
    if (t < M) {
        int g = blockIdx.x*M + t;
        px = pos0[2*g]; py = pos0[2*g+1]; wx = wind[2*g]; wy = wind[2*g+1];
    }

    float F[2][16];   // fetch double-buffer (statically indexed under full unroll)

    // ---- priming: S <- w2 chunk0; F[1] <- w2 chunk1; obs(step 0) ----
    FETCH_CHUNK(w2, 0, F[0]);
    WRITE_CHUNK(F[0]);
    FETCH_CHUNK(w2, 1, F[1]);
    if (t < M) { OBS_WRITE(); }

    f32x4 acc[4][4];

    for (int step = 0; step < HORIZON; ++step) {
        __syncthreads();   // B_A: obs + S(w2c0) visible; paL consumed

        // ---- L1: obs(13 pad 32) x w1 -> acc ----
        #pragma unroll
        for (int mt = 0; mt < 4; ++mt)
          #pragma unroll
          for (int nt = 0; nt < 4; ++nt)
            acc[mt][nt] = (f32x4){b1r[nt], b1r[nt], b1r[nt], b1r[nt]};
        {
            f16x8 ah[4], al[4];
            #pragma unroll
            for (int mt = 0; mt < 4; ++mt) {
                int off = (64*rh + 16*mt + lr)*40 + q*8;
                ah[mt] = *(const f16x8*)(hA_hi + off);
                al[mt] = *(const f16x8*)(hA_lo + off);
            }
            #pragma unroll
            for (int nt = 0; nt < 4; ++nt)
              #pragma unroll
              for (int mt = 0; mt < 4; ++mt)
                mfma3(acc[mt][nt], ah[mt], al[mt], w1h[nt], w1l[nt]);
        }
        __syncthreads();   // B_B: obs reads done -> hA writable
        WRITEBACK_ACC();   // h1 -> hA
        #pragma unroll
        for (int mt = 0; mt < 4; ++mt)
          #pragma unroll
          for (int nt = 0; nt < 4; ++nt)
            acc[mt][nt] = (f32x4){b2r[nt], b2r[nt], b2r[nt], b2r[nt]};
        __syncthreads();   // B_C: h1 + S(w2c0) ready

        // ---- unified 16-chunk L2+L3 pipeline (wraps into next step's w2c0/c1) ----
        #pragma unroll
        for (int g = 0; g < 16; ++g) {
            const int cf = (g + 2) & 15;           // chunk to fetch (2 ahead)
            if (cf & 8) { FETCH_CHUNK(w3, cf & 7, F[g & 1]); }
            else        { FETCH_CHUNK(w2, cf & 7, F[g & 1]); }

            const int kcl = g & 7;
            f16x8 ah[4], al[4];
            #pragma unroll
            for (int mt = 0; mt < 4; ++mt) {
                int row = 64*rh + 16*mt + lr;
                int off = row*256 + (((kcl*4 + q) ^ (row & 31)) << 3);
                ah[mt] = *(const f16x8*)(hA_hi + off);
                al[mt] = *(const f16x8*)(hA_lo + off);
            }
            #pragma unroll
            for (int nt = 0; nt < 4; ++nt) {
                int boff = (q*256 + 64*cq + 16*nt + lr)*8;
                f16x8 bh = *(const f16x8*)(S_hi + boff);
                f16x8 bl = *(const f16x8*)(S_lo + boff);
                #pragma unroll
                for (int mt = 0; mt < 4; ++mt)
                    mfma3(acc[mt][nt], ah[mt], al[mt], bh, bl);
            }
            __syncthreads();             // S reads done; fetch (issued above) drained under MFMA
            if (g == 7) {
                WRITEBACK_ACC();         // h2 -> hA (reads done at barrier above)
                #pragma unroll
                for (int mt = 0; mt < 4; ++mt)
                  #pragma unroll
                  for (int nt = 0; nt < 4; ++nt)
                    acc[mt][nt] = (f32x4){b3r[nt], b3r[nt], b3r[nt], b3r[nt]};
            }
            WRITE_CHUNK(F[(g + 1) & 1]); // S <- chunk g+1
            __syncthreads();             // S ready (+ h2 visible when g==7)
        }

        // ---- fused L4: partials from relu(acc=h3) in registers ----
        {
            float pa[4][4][2];
            #pragma unroll
            for (int mt = 0; mt < 4; ++mt)
              #pragma unroll
              for (int r = 0; r < 4; ++r)
                { pa[mt][r][0] = 0.f; pa[mt][r][1] = 0.f; }
            #pragma unroll
            for (int mt = 0; mt < 4; ++mt)
              #pragma unroll
              for (int nt = 0; nt < 4; ++nt)
                #pragma unroll
                for (int r = 0; r < 4; ++r) {
                    float h = fmaxf(acc[mt][nt][r], 0.f);
                    pa[mt][r][0] = fmaf(h, wmur[nt][0], pa[mt][r][0]);
                    pa[mt][r][1] = fmaf(h, wmur[nt][1], pa[mt][r][1]);
                }
            #pragma unroll
            for (int s = 0; s < 4; ++s)
                #pragma unroll
                for (int mt = 0; mt < 4; ++mt)
                  #pragma unroll
                  for (int r = 0; r < 4; ++r) {
                      pa[mt][r][0] += __shfl_xor(pa[mt][r][0], 1 << s, 64);
                      pa[mt][r][1] += __shfl_xor(pa[mt][r][1], 1 << s, 64);
                  }
            if (lr == 0) {
                #pragma unroll
                for (int mt = 0; mt < 4; ++mt)
                  #pragma unroll
                  for (int c = 0; c < 2; ++c) {
                      f32x4 v = {pa[mt][0][c], pa[mt][1][c], pa[mt][2][c], pa[mt][3][c]};
                      *(f32x4*)&paL[(cq*2 + c)*128 + 64*rh + 16*mt + 4*q] = v;
                  }
            }
        }
        __syncthreads();   // B_D: paL visible; all hA reads done

        // ---- P5 + P0: action, dynamics, STREL, next obs ----
        if (t < M) {
            float s0 = bm0 + paL[0*128 + t] + paL[2*128 + t] + paL[4*128 + t] + paL[6*128 + t];
            float s1 = bm1 + paL[1*128 + t] + paL[3*128 + t] + paL[5*128 + t] + paL[7*128 + t];
            float ax = fminf(fmaxf(s0, -1.f), 1.f);
            float ay = fminf(fmaxf(s1, -1.f), 1.f);
            float vx = 2.f*ax + wx, vy = 2.f*ay + wy;
            #pragma unroll
            for (int s = 0; s < 4; ++s) {
                px = fminf(fmaxf(px + 0.0625f*vx, -4.f), 10.f);
                py = fminf(fmaxf(py + 0.0625f*vy, -4.f), 10.f);
            }
            float dx0 = px - 1.75f, dy0 = py - 1.75f;
            float dx1 = px - 1.75f, dy1 = py - 3.75f;
            float dx2 = px - 3.75f, dy2 = py - 2.00f;
            float c0 = sqrtf(dx0*dx0+dy0*dy0+1e-9f) - 0.38f;
            float c1 = sqrtf(dx1*dx1+dy1*dy1+1e-9f) - 0.42f;
            float c2 = sqrtf(dx2*dx2+dy2*dy2+1e-9f) - 0.34f;
            float cmin = fminf(c0, fminf(c1, c2));
            float ssum = expf(-50.f*(c0-cmin)) + expf(-50.f*(c1-cmin)) + expf(-50.f*(c2-cmin));
            float safe = cmin - logf(ssum)/50.f;
            float gdx = px - 4.f, gdy = py - 3.f;
            float reach = 0.45f - sqrtf(gdx*gdx+gdy*gdy+1e-9f);
            float xs = -8.f*safe;
            if (xs > mx_s) { sum_s = sum_s*expf(mx_s - xs) + 1.f; mx_s = xs; }
            else           { sum_s += expf(xs - mx_s); }
            float xr = 8.f*reach;
            if (xr > mx_r) { sum_r = sum_r*expf(mx_r - xr) + 1.f; mx_r = xr; }
            else           { sum_r += expf(xr - mx_r); }
            OBS_WRITE();   // obs for next step (last iteration: dead write, harmless)
        }
    }

    if (t < M) {
        float rs = -(mx_s + logf(sum_s)) * 0.125f;
        float rr =  (mx_r + logf(sum_r)) * 0.125f;
        float u0 = -8.f*rs, u1 = -8.f*rr;
        float mu = fmaxf(u0, u1);
        float rho = -(mu + logf(expf(u0-mu) + expf(u1-mu))) * 0.125f;
        out[blockIdx.x*M + t] = rho;
    }
}

} // namespace

extern "C" void kernel_launch(void* const* d_in, const int* in_sizes, int n_in,
                              void* d_out, int out_size, void* d_ws, size_t ws_size,
                              hipStream_t stream)
{
    const float* pos0 = (const float*)d_in[0];
    const float* wind = (const float*)d_in[1];
    const float* w1   = (const float*)d_in[2];
    const float* b1   = (const float*)d_in[3];
    const float* w2   = (const float*)d_in[4];
    const float* b2   = (const float*)d_in[5];
    const float* w3   = (const float*)d_in[6];
    const float* b3   = (const float*)d_in[7];
    const float* wmu  = (const float*)d_in[8];
    const float* bmu  = (const float*)d_in[9];
    float* out = (float*)d_out;
    (void)d_ws; (void)ws_size;

    const int B = in_sizes[0] / 2;     // 32768 agents
    const int blocks = B / M;          // 256 blocks, exactly 1/CU
    rollout_kernel<<<blocks, NT, 0, stream>>>(pos0, wind, w1, b1, w2, b2,
                                              w3, b3, wmu, bmu, out);
}